// Round 7
// baseline (295.372 us; speedup 1.0000x reference)
//
#include <hip/hip_runtime.h>

// ---- problem constants ----
#define BATCH 8
#define CIN   512
#define NH    8
#define DH    128
#define PP    1024   // 32*32 positions
#define QK_SCALE 0.08838834764831845f  // 128^-0.5
#define LOG2E 1.4426950408889634f

typedef unsigned int  u32;
typedef unsigned short u16;
typedef __attribute__((ext_vector_type(8)))  short short8;
typedef __attribute__((ext_vector_type(16))) float f32x16;
typedef __attribute__((ext_vector_type(4)))  u32 u32x4;

typedef __attribute__((address_space(1))) const u32 GU32;
typedef __attribute__((address_space(3))) u32 LU32;

// workspace layout (bytes):
//   Qhi    [64][1024][128] u16   @ 0        (16 MB)   (Q pre-scaled by QK_SCALE*LOG2E)
//   Qlo    [64][1024][128] u16   @ 16 MB    (16 MB)
//   KIMG   [64*32][16384]  char  @ 32 MB    (32 MB)  per-tile: hi 8KB, lo 8KB
//   VIMG   [64*32][16384]  char  @ 64 MB    (32 MB)
//   R      [64][1024][64]  f32   @ 96 MB    (16 MB)  } overlaid: FIMG dead before
//   FIMG   [8*8*16][16384] char  @ 96 MB    (16 MB)  } rel_gemm writes R
//   AIMG   [24*16][16384]  char  @ 112 MB   (6.3 MB)
//   RELIMG [128 rows]      char  @ 119 MB   (64 KB)

__device__ inline u32 f2bf(float x) {            // fp32 -> bf16 (RNE)
    u32 u = __float_as_uint(x);
    return (u + 0x7fffu + ((u >> 16) & 1u)) >> 16;
}
__device__ inline float bf2f(u32 h) { return __uint_as_float(h << 16); }

__device__ inline u32 cvtpk(float a, float b) {  // D[15:0]=bf16(a), D[31:16]=bf16(b)
    u32 r; asm("v_cvt_pk_bf16_f32 %0, %1, %2" : "=v"(r) : "v"(a), "v"(b)); return r;
}
__device__ inline void split2(float a, float b, u32& wh, u32& wl) {
    u32 h = cvtpk(a, b);
    float ha = __uint_as_float(h << 16);
    float hb = __uint_as_float(h & 0xffff0000u);
    wl = cvtpk(a - ha, b - hb);
    wh = h;
}

__device__ inline void cvt8(const float* v, float scl, uint4& hv, uint4& lv) {
    u32 h[8], l[8];
#pragma unroll
    for (int j = 0; j < 8; ++j) {
        float x = v[j] * scl;
        u32 hb = f2bf(x);
        float hf = bf2f(hb);
        u32 lb = f2bf(x - hf);
        h[j] = hb; l[j] = lb;
    }
    hv = make_uint4(h[0] | (h[1] << 16), h[2] | (h[3] << 16),
                    h[4] | (h[5] << 16), h[6] | (h[7] << 16));
    lv = make_uint4(l[0] | (l[1] << 16), l[2] | (l[3] << 16),
                    l[4] | (l[5] << 16), l[6] | (l[7] << 16));
}

// ============================================================================
// Kernel 0a: W -> AIMG (bf16 hi/lo split; Q rows pre-scaled by QK_SCALE*LOG2E
// so attention logits are already in log2 units -> softmax uses exp2).
// ============================================================================
__global__ __launch_bounds__(256) void wconv(
    const float* __restrict__ w, char* __restrict__ AIMG)
{
    const int gid = blockIdx.x * 256 + threadIdx.x;    // 196608 granules
    const int o  = gid >> 6;
    const int c0 = (gid & 63) << 3;
    const float scl = (o < 1024) ? QK_SCALE * LOG2E : 1.0f;
    float v[8];
    float4 v0 = *(const float4*)(w + (size_t)o * CIN + c0);
    float4 v1 = *(const float4*)(w + (size_t)o * CIN + c0 + 4);
    v[0]=v0.x; v[1]=v0.y; v[2]=v0.z; v[3]=v0.w;
    v[4]=v1.x; v[5]=v1.y; v[6]=v1.z; v[7]=v1.w;
    uint4 hv, lv; cvt8(v, scl, hv, lv);
    const int otile = o >> 7, row = o & 127, chunk = c0 >> 5, g = (c0 >> 3) & 3;
    char* base = AIMG + (size_t)(otile * 16 + chunk) * 16384
               + row * 64 + ((g ^ (row & 3)) << 4);
    *(uint4*)(base)        = hv;
    *(uint4*)(base + 8192) = lv;
}

// ============================================================================
// Kernel 0b: fm -> FIMG (transpose via LDS + bf16 hi/lo split). (unchanged)
// ============================================================================
__global__ __launch_bounds__(256) void fmconv(
    const float* __restrict__ fm, char* __restrict__ FIMG)
{
    __shared__ float Fs[32][128];
    const int t = threadIdx.x;
    const int chunk = blockIdx.x, ptile = blockIdx.y, b = blockIdx.z;
    const float* src = fm + ((size_t)(b * CIN + chunk * 32)) * PP + ptile * 128;
#pragma unroll
    for (int ii = 0; ii < 4; ++ii) {
        int idx = t + 256 * ii;                 // 1024 float4 = 32c x 128p
        int c = idx >> 5, p4 = idx & 31;
        *(float4*)(&Fs[c][p4 * 4]) = *(const float4*)(src + (size_t)c * PP + p4 * 4);
    }
    __syncthreads();
    const int p = t & 127, gb = (t >> 7) * 2;
#pragma unroll
    for (int gi = 0; gi < 2; ++gi) {
        const int g = gb + gi;
        float v[8];
#pragma unroll
        for (int j = 0; j < 8; ++j) v[j] = Fs[g * 8 + j][p];   // 2-way: free
        uint4 hv, lv; cvt8(v, 1.0f, hv, lv);
        char* base = FIMG + (size_t)((b * 8 + ptile) * 16 + chunk) * 16384
                   + p * 64 + ((g ^ (p & 3)) << 4);
        *(uint4*)(base)        = hv;
        *(uint4*)(base + 8192) = lv;
    }
}

// ============================================================================
// Kernel 0c: relH/relW -> RELIMG (relcat image). (unchanged)
// ============================================================================
__global__ __launch_bounds__(256) void relprep(
    const float* __restrict__ relH, const float* __restrict__ relW,
    char* __restrict__ RELIMG)
{
    const int idx = blockIdx.x * 256 + threadIdx.x;   // 2048 granules
    const int r = idx >> 4, g = idx & 15;
    float v[8];
    if (r < 63) {
        float4 v0 = *(const float4*)(relH + (size_t)r * DH + g * 8);
        float4 v1 = *(const float4*)(relH + (size_t)r * DH + g * 8 + 4);
        v[0]=v0.x; v[1]=v0.y; v[2]=v0.z; v[3]=v0.w;
        v[4]=v1.x; v[5]=v1.y; v[6]=v1.z; v[7]=v1.w;
    } else if (r < 126) {
        float4 v0 = *(const float4*)(relW + (size_t)(r - 63) * DH + g * 8);
        float4 v1 = *(const float4*)(relW + (size_t)(r - 63) * DH + g * 8 + 4);
        v[0]=v0.x; v[1]=v0.y; v[2]=v0.z; v[3]=v0.w;
        v[4]=v1.x; v[5]=v1.y; v[6]=v1.z; v[7]=v1.w;
    } else {
#pragma unroll
        for (int j = 0; j < 8; ++j) v[j] = 0.f;
    }
    uint4 hv, lv; cvt8(v, 1.0f, hv, lv);
    char* base = RELIMG + r * 256 + ((g ^ (r & 15)) << 4);
    *(uint4*)(base)         = hv;
    *(uint4*)(base + 32768) = lv;
}

// ============================================================================
// Kernel 1: QKV projection as split-bf16 MFMA GEMM (unchanged).
// ============================================================================
__global__ __launch_bounds__(256, 2) void qkv_gemm(
    const char* __restrict__ AIMG, const char* __restrict__ FIMG,
    u16* __restrict__ Qhi, u16* __restrict__ Qlo,
    char* __restrict__ KIMG, char* __restrict__ VIMG)
{
    __shared__ char lds[65536];       // 2 x (A 16KB | B 16KB); reused as Cs

    const int t = threadIdx.x, lane = t & 63, wid = t >> 6;
    const int l31 = lane & 31, h5 = lane >> 5;
    const int ptile = blockIdx.x, otile = blockIdx.y, b = blockIdx.z;
    const int wr = wid >> 1, wc = wid & 1;

    const char* Achunks = AIMG + (size_t)(otile * 16) * 16384;
    const char* Bchunks = FIMG + (size_t)((b * 8 + ptile) * 16) * 16384;

    const int half = wid & 1;
    const char* srcTile = (wid < 2) ? Achunks : Bchunks;
    char* dstBase0 = lds + ((wid < 2) ? 0 : 16384) + half * 8192;   // wave-uniform

    auto stageChunk = [&](int chunk, int par) {
        const char* src = srcTile + (size_t)chunk * 16384 + half * 8192 + lane * 16;
        char* dst = dstBase0 + par * 32768;
#pragma unroll
        for (int c = 0; c < 8; ++c)
            __builtin_amdgcn_global_load_lds((GU32*)(src + c * 1024),
                                             (LU32*)(dst + c * 1024), 16, 0, 0);
    };

    f32x16 acc[2][2];
#pragma unroll
    for (int i = 0; i < 2; ++i)
#pragma unroll
        for (int j = 0; j < 2; ++j)
#pragma unroll
            for (int r = 0; r < 16; ++r) acc[i][j][r] = 0.f;

    auto computeChunk = [&](int par) {
        const char* Abuf = lds + par * 32768;
        const char* Bbuf = Abuf + 16384;
#pragma unroll
        for (int ks = 0; ks < 2; ++ks) {
            short8 a_h[2], a_l[2], b_h[2], b_l[2];
#pragma unroll
            for (int ot = 0; ot < 2; ++ot) {
                const int row = wr * 64 + ot * 32 + l31;
                const int off = row * 64 + (((ks * 2 + h5) ^ (row & 3)) << 4);
                a_h[ot] = *(const short8*)(Abuf + off);
                a_l[ot] = *(const short8*)(Abuf + 8192 + off);
            }
#pragma unroll
            for (int pt = 0; pt < 2; ++pt) {
                const int col = wc * 64 + pt * 32 + l31;
                const int off = col * 64 + (((ks * 2 + h5) ^ (col & 3)) << 4);
                b_h[pt] = *(const short8*)(Bbuf + off);
                b_l[pt] = *(const short8*)(Bbuf + 8192 + off);
            }
#pragma unroll
            for (int ot = 0; ot < 2; ++ot)
#pragma unroll
                for (int pt = 0; pt < 2; ++pt) {
                    acc[ot][pt] = __builtin_amdgcn_mfma_f32_32x32x16_bf16(a_h[ot], b_h[pt], acc[ot][pt], 0, 0, 0);
                    acc[ot][pt] = __builtin_amdgcn_mfma_f32_32x32x16_bf16(a_h[ot], b_l[pt], acc[ot][pt], 0, 0, 0);
                    acc[ot][pt] = __builtin_amdgcn_mfma_f32_32x32x16_bf16(a_l[ot], b_h[pt], acc[ot][pt], 0, 0, 0);
                }
        }
    };

    stageChunk(0, 0);
    for (int ch = 0; ch < 15; ++ch) {
        stageChunk(ch + 1, (ch + 1) & 1);
        asm volatile("s_waitcnt vmcnt(8)" ::: "memory");
        __builtin_amdgcn_sched_barrier(0);
        __builtin_amdgcn_s_barrier();
        __builtin_amdgcn_sched_barrier(0);
        computeChunk(ch & 1);
        __builtin_amdgcn_s_barrier();
        __builtin_amdgcn_sched_barrier(0);
    }
    asm volatile("s_waitcnt vmcnt(0)" ::: "memory");
    __builtin_amdgcn_sched_barrier(0);
    __builtin_amdgcn_s_barrier();
    __builtin_amdgcn_sched_barrier(0);
    computeChunk(1);                  // chunk 15
    __syncthreads();                  // all frag reads done; LDS -> Cs

    // ---- restage C tile (fp32, XOR-swizzled): Cs[o*128 + (p ^ (o&31))]
    float* Cs = (float*)lds;
#pragma unroll
    for (int ot = 0; ot < 2; ++ot)
#pragma unroll
        for (int pt = 0; pt < 2; ++pt)
#pragma unroll
            for (int r = 0; r < 16; ++r) {
                const int o = wr * 64 + ot * 32 + (r & 3) + 8 * (r >> 2) + 4 * h5;
                const int p = wc * 64 + pt * 32 + l31;
                Cs[o * 128 + (p ^ (o & 31))] = acc[ot][pt][r];
            }
    __syncthreads();

    const int tsel = otile >> 3;      // 0=Q 1=K 2=V
    const int n    = otile & 7;
    const int bn   = b * NH + n;

    if (tsel == 0) {
        const int d0 = (t & 15) * 8, prow = t >> 4;
#pragma unroll
        for (int i = 0; i < 8; ++i) {
            const int p = prow + 16 * i;
            float v[8];
#pragma unroll
            for (int j = 0; j < 8; ++j)
                v[j] = Cs[(d0 + j) * 128 + (p ^ ((d0 + j) & 31))];
            uint4 hv, lv; cvt8(v, 1.0f, hv, lv);
            const size_t off = ((size_t)bn * PP + ptile * 128 + p) * DH + d0;
            *(uint4*)(Qhi + off) = hv;
            *(uint4*)(Qlo + off) = lv;
        }
    } else if (tsel == 1) {
        const int d0 = (t & 15) * 8, prow = t >> 4;
#pragma unroll
        for (int i = 0; i < 8; ++i) {
            const int p = prow + 16 * i;
            float v[8];
#pragma unroll
            for (int j = 0; j < 8; ++j)
                v[j] = Cs[(d0 + j) * 128 + (p ^ ((d0 + j) & 31))];
            uint4 hv, lv; cvt8(v, 1.0f, hv, lv);
            const int kt = ptile * 4 + (p >> 5), r32 = p & 31;
            char* base = KIMG + ((size_t)(bn * 32 + kt) << 14)
                       + r32 * 256 + (((d0 >> 3) ^ (r32 & 15)) << 4);
            *(uint4*)(base)        = hv;
            *(uint4*)(base + 8192) = lv;
        }
    } else {
        const int g = t & 3, dbase = t >> 2;
#pragma unroll
        for (int i = 0; i < 2; ++i) {
            const int d = dbase + 64 * i;
#pragma unroll
            for (int ks = 0; ks < 4; ++ks) {
                const int p0 = ks * 32 + g * 8;
                float v[8];
#pragma unroll
                for (int j = 0; j < 8; ++j)
                    v[j] = Cs[d * 128 + ((p0 + j) ^ (d & 31))];
                uint4 hv, lv; cvt8(v, 1.0f, hv, lv);
                char* base = VIMG + ((size_t)(bn * 32 + ptile * 4 + ks) << 14)
                           + d * 64 + ((g ^ (d & 3)) << 4);
                *(uint4*)(base)        = hv;
                *(uint4*)(base + 8192) = lv;
            }
        }
    }
}

// ============================================================================
// Kernel 2: rel logits as split-bf16 MFMA GEMM + in-LDS window scatter.
// (unchanged; note R inherits the LOG2E scale from Q automatically)
// ============================================================================
__global__ __launch_bounds__(256, 1) void rel_gemm(
    const u16* __restrict__ Qhi, const u16* __restrict__ Qlo,
    const char* __restrict__ RELIMG, float* __restrict__ R)
{
    __shared__ char lds[131072];
    const int t = threadIdx.x, lane = t & 63, wid = t >> 6;
    const int l31 = lane & 31, h5 = lane >> 5;
    const int bn = blockIdx.y, p0 = blockIdx.x * 128;

    {
        const char* src = RELIMG + wid * 16384 + lane * 16;
        char* dst = lds + wid * 16384;
#pragma unroll
        for (int c = 0; c < 16; ++c)
            __builtin_amdgcn_global_load_lds((GU32*)(src + c * 1024),
                                             (LU32*)(dst + c * 1024), 16, 0, 0);
    }
#pragma unroll
    for (int pt = 0; pt < 4; ++pt) {
#pragma unroll
        for (int half = 0; half < 2; ++half) {
            const u16* srcp = (half ? Qlo : Qhi) + ((size_t)bn * PP + p0 + pt * 32) * DH;
            char* dstb = lds + 65536 + pt * 16384 + half * 8192;
#pragma unroll
            for (int ii = 0; ii < 2; ++ii) {
                const int f = t + 256 * ii;              // granule 0..511
                const int p = f >> 4, g = f & 15;
                uint4 v = *(const uint4*)((const char*)srcp + f * 16);
                *(uint4*)(dstb + p * 256 + ((g ^ (p & 15)) << 4)) = v;
            }
        }
    }
    asm volatile("s_waitcnt vmcnt(0) lgkmcnt(0)" ::: "memory");
    __builtin_amdgcn_s_barrier();
    __builtin_amdgcn_sched_barrier(0);

    f32x16 acc[4];
#pragma unroll
    for (int i = 0; i < 4; ++i)
#pragma unroll
        for (int r = 0; r < 16; ++r) acc[i][r] = 0.f;

    const int rrow = wid * 32 + l31;
#pragma unroll
    for (int kk = 0; kk < 8; ++kk) {
        const int g = kk * 2 + h5;
        const int aoff = rrow * 256 + ((g ^ (rrow & 15)) << 4);
        short8 ah = *(const short8*)(lds + aoff);
        short8 al = *(const short8*)(lds + 32768 + aoff);
        const int boff = l31 * 256 + ((g ^ (l31 & 15)) << 4);
#pragma unroll
        for (int pt = 0; pt < 4; ++pt) {
            const char* bb = lds + 65536 + pt * 16384;
            short8 bh = *(const short8*)(bb + boff);
            short8 bl = *(const short8*)(bb + 8192 + boff);
            acc[pt] = __builtin_amdgcn_mfma_f32_32x32x16_bf16(ah, bh, acc[pt], 0, 0, 0);
            acc[pt] = __builtin_amdgcn_mfma_f32_32x32x16_bf16(ah, bl, acc[pt], 0, 0, 0);
            acc[pt] = __builtin_amdgcn_mfma_f32_32x32x16_bf16(al, bh, acc[pt], 0, 0, 0);
        }
    }
    __syncthreads();                  // all LDS reads done -> overlay Cs

    float* Cs = (float*)lds;          // [128 j'][132] padded
#pragma unroll
    for (int pt = 0; pt < 4; ++pt)
#pragma unroll
        for (int r = 0; r < 16; ++r) {
            const int jr = wid * 32 + (r & 3) + 8 * (r >> 2) + 4 * h5;
            Cs[jr * 132 + pt * 32 + l31] = acc[pt][r];
        }
    __syncthreads();

    const int pl = t >> 1, jh = t & 1;
    const int pg = p0 + pl, hq = pg >> 5, wq = pg & 31;
    const int base = jh ? (94 - wq) : (31 - hq);
    float* dst = R + ((size_t)bn * PP + pg) * 64 + jh * 32;
#pragma unroll
    for (int j4 = 0; j4 < 8; ++j4) {
        float4 v;
        v.x = Cs[(base + j4 * 4 + 0) * 132 + pl];
        v.y = Cs[(base + j4 * 4 + 1) * 132 + pl];
        v.z = Cs[(base + j4 * 4 + 2) * 132 + pl];
        v.w = Cs[(base + j4 * 4 + 3) * 132 + pl];
        *(float4*)(dst + j4 * 4) = v;
    }
}

// ============================================================================
// Kernel 3: split-bf16 MFMA flash attention, att[2] double-pipeline (T15).
// Per iter t: stage K(t+2)/V(t+1); vmcnt(8)+barrier (covers K(t+1),V(t));
// QK(t+1)->s_next on MFMA pipe WHILE softmax(t) runs on VALU; PV(t);
// one tail barrier. 2 barriers/iter (was 3). exp2-domain softmax.
// LDS 80KB: kbuf0 16K | kbuf1 16K | vbuf0 16K | vbuf1 16K | R1 16K
// ============================================================================
__global__ __launch_bounds__(256, 2) void attn_kernel(
    const u16* __restrict__ Qhi, const u16* __restrict__ Qlo,
    const char* __restrict__ KIMG, const char* __restrict__ VIMG,
    const float* __restrict__ R, float* __restrict__ out)
{
    __shared__ char lds[81920];

    const int t    = threadIdx.x;
    const int lane = t & 63, wid = t >> 6;
    // XCD swizzle: lin = c*64 + m*8 + r  ->  bn = r*8+c (XCD r), q-tile = m
    const int lin = blockIdx.x;
    const int bn  = (lin & 7) * 8 + (lin >> 6);
    const int q0  = ((lin >> 3) & 7) * 128;
    const int b  = bn >> 3,  n = bn & 7;
    const int l31 = lane & 31, h5 = lane >> 5;
    const int q_local = wid * 32 + l31;
    const int q = q0 + q_local;

    short8 qh[8], ql[8];
    {
        const u16* qrh = Qhi + ((size_t)bn * PP + q) * DH + h5 * 8;
        const u16* qrl = Qlo + ((size_t)bn * PP + q) * DH + h5 * 8;
#pragma unroll
        for (int kk = 0; kk < 8; ++kk) {
            qh[kk] = *(const short8*)(qrh + kk * 16);
            ql[kk] = *(const short8*)(qrl + kk * 16);
        }
    }
    float R2a[16];
    {
        const float* r2p = R + ((size_t)bn * PP + q) * 64 + 32 + h5 * 4;
#pragma unroll
        for (int m_ = 0; m_ < 4; ++m_) {
            float4 v = *(const float4*)(r2p + m_ * 8);
            R2a[m_*4+0] = v.x; R2a[m_*4+1] = v.y; R2a[m_*4+2] = v.z; R2a[m_*4+3] = v.w;
        }
    }
    float* R1p = (float*)(lds + 65536);
    {
#pragma unroll
        for (int r = 0; r < 4; ++r) {
            int idx = t + 256 * r;
            int row = idx >> 3, c4 = (idx & 7) * 4;
            float4 v = *(const float4*)(R + ((size_t)bn * PP + q0 + row) * 64 + c4);
            R1p[row * 32 + ((c4 + 0) ^ (row & 31))] = v.x;
            R1p[row * 32 + ((c4 + 1) ^ (row & 31))] = v.y;
            R1p[row * 32 + ((c4 + 2) ^ (row & 31))] = v.z;
            R1p[row * 32 + ((c4 + 3) ^ (row & 31))] = v.w;
        }
    }

    auto issueK = [&](int kt, int par) {
        const char* src = KIMG + (((size_t)bn * 32 + kt) << 14) + wid * 4096 + lane * 16;
        const char* dst = lds + par * 16384 + wid * 4096;
#pragma unroll
        for (int c = 0; c < 4; ++c)
            __builtin_amdgcn_global_load_lds((GU32*)(src + c * 1024),
                                             (LU32*)(dst + c * 1024), 16, 0, 0);
    };
    auto issueV = [&](int kt, int par) {
        const char* src = VIMG + (((size_t)bn * 32 + kt) << 14) + wid * 4096 + lane * 16;
        const char* dst = lds + 32768 + par * 16384 + wid * 4096;
#pragma unroll
        for (int c = 0; c < 4; ++c)
            __builtin_amdgcn_global_load_lds((GU32*)(src + c * 1024),
                                             (LU32*)(dst + c * 1024), 16, 0, 0);
    };

    issueK(0, 0);
    asm volatile("s_waitcnt lgkmcnt(0)" ::: "memory");   // R1 ds_writes done
    __builtin_amdgcn_s_barrier();                        // R1 visible
    __builtin_amdgcn_sched_barrier(0);
    issueV(0, 0);
    issueK(1, 1);
    asm volatile("s_waitcnt vmcnt(8)" ::: "memory");     // K(0) (+Q/R loads) landed
    __builtin_amdgcn_sched_barrier(0);
    __builtin_amdgcn_s_barrier();
    __builtin_amdgcn_sched_barrier(0);

    f32x16 o_[4];
#pragma unroll
    for (int i = 0; i < 4; ++i)
#pragma unroll
        for (int r = 0; r < 16; ++r) o_[i][r] = 0.f;

    float m_run = -1e30f, l_run = 0.f;
    f32x16 sA, sB;

    // prologue QK(0) -> sA  (kbuf0)
#pragma unroll
    for (int r = 0; r < 16; ++r) sA[r] = 0.f;
    {
        const char* kb = lds;
        __builtin_amdgcn_s_setprio(1);
#pragma unroll
        for (int kk = 0; kk < 8; ++kk) {
            const int g = kk * 2 + h5;
            const int off = l31 * 256 + ((g ^ (l31 & 15)) << 4);
            short8 kh = *(const short8*)(kb + off);
            short8 kl = *(const short8*)(kb + 8192 + off);
            sA = __builtin_amdgcn_mfma_f32_32x32x16_bf16(kh, qh[kk], sA, 0, 0, 0);
            sA = __builtin_amdgcn_mfma_f32_32x32x16_bf16(kh, ql[kk], sA, 0, 0, 0);
            sA = __builtin_amdgcn_mfma_f32_32x32x16_bf16(kl, qh[kk], sA, 0, 0, 0);
        }
        __builtin_amdgcn_s_setprio(0);
    }
    __builtin_amdgcn_s_barrier();        // all waves done reading kbuf0
    __builtin_amdgcn_sched_barrier(0);

#define ATTN_ITER(T, SCUR, SNEXT, PAR)                                          \
    {                                                                           \
        issueV(((T) + 1) & 31, (PAR) ^ 1);                                      \
        issueK(((T) + 2) & 31, (PAR));                                          \
        asm volatile("s_waitcnt vmcnt(8)" ::: "memory"); /* K(T+1),V(T) in */   \
        __builtin_amdgcn_sched_barrier(0);                                      \
        __builtin_amdgcn_s_barrier();                                           \
        __builtin_amdgcn_sched_barrier(0);                                      \
        /* QK(T+1) -> SNEXT : MFMA pipe, overlaps softmax(T) VALU below */      \
        _Pragma("unroll")                                                       \
        for (int r = 0; r < 16; ++r) SNEXT[r] = 0.f;                            \
        {                                                                       \
            const char* kb = lds + ((PAR) ^ 1) * 16384;                         \
            __builtin_amdgcn_s_setprio(1);                                      \
            _Pragma("unroll")                                                   \
            for (int kk = 0; kk < 8; ++kk) {                                    \
                const int g = kk * 2 + h5;                                      \
                const int off = l31 * 256 + ((g ^ (l31 & 15)) << 4);            \
                short8 kh = *(const short8*)(kb + off);                         \
                short8 kl = *(const short8*)(kb + 8192 + off);                  \
                SNEXT = __builtin_amdgcn_mfma_f32_32x32x16_bf16(kh, qh[kk], SNEXT, 0, 0, 0); \
                SNEXT = __builtin_amdgcn_mfma_f32_32x32x16_bf16(kh, ql[kk], SNEXT, 0, 0, 0); \
                SNEXT = __builtin_amdgcn_mfma_f32_32x32x16_bf16(kl, qh[kk], SNEXT, 0, 0, 0); \
            }                                                                   \
            __builtin_amdgcn_s_setprio(0);                                      \
        }                                                                       \
        /* softmax(T) on SCUR (log2 domain) */                                  \
        const float r1 = R1p[q_local * 32 + ((T) ^ l31)];                       \
        float mx = -1e30f;                                                      \
        _Pragma("unroll")                                                       \
        for (int r = 0; r < 16; ++r) {                                          \
            SCUR[r] += R2a[r];                                                  \
            mx = fmaxf(mx, SCUR[r]);                                            \
        }                                                                       \
        mx = fmaxf(mx, __shfl_xor(mx, 32));                                     \
        const float pmax = mx + r1;                                             \
        if (__any(pmax > m_run + 11.5415603f)) {   /* 8*log2e */                \
            const float m_new = fmaxf(m_run, pmax);                             \
            const float alpha = exp2f(m_run - m_new);                           \
            l_run *= alpha;                                                     \
            _Pragma("unroll")                                                   \
            for (int i = 0; i < 4; ++i)                                         \
                _Pragma("unroll")                                               \
                for (int r = 0; r < 16; ++r) o_[i][r] *= alpha;                 \
            m_run = m_new;                                                      \
        }                                                                       \
        const float tsh = r1 - m_run;                                           \
        float pf[16];                                                           \
        float rsum = 0.f;                                                       \
        _Pragma("unroll")                                                       \
        for (int r = 0; r < 16; ++r) {                                          \
            float p = exp2f(SCUR[r] + tsh);                                     \
            rsum += p;                                                          \
            pf[r] = p;                                                          \
        }                                                                       \
        rsum += __shfl_xor(rsum, 32);                                           \
        l_run += rsum;                                                          \
        short8 pH[2], pL[2];                                                    \
        _Pragma("unroll")                                                       \
        for (int kk2 = 0; kk2 < 2; ++kk2) {                                     \
            const int b8 = kk2 * 8;                                             \
            u32 h0, l0, h1, l1, h2, l2, h3, l3;                                 \
            split2(pf[b8 + 0], pf[b8 + 1], h0, l0);                             \
            split2(pf[b8 + 2], pf[b8 + 3], h1, l1);                             \
            split2(pf[b8 + 4], pf[b8 + 5], h2, l2);                             \
            split2(pf[b8 + 6], pf[b8 + 7], h3, l3);                             \
            asm("v_permlane32_swap_b32 %0, %1" : "+v"(h0), "+v"(h2));           \
            asm("v_permlane32_swap_b32 %0, %1" : "+v"(h1), "+v"(h3));           \
            asm("v_permlane32_swap_b32 %0, %1" : "+v"(l0), "+v"(l2));           \
            asm("v_permlane32_swap_b32 %0, %1" : "+v"(l1), "+v"(l3));           \
            u32x4 vh4 = {h0, h1, h2, h3};                                       \
            u32x4 vl4 = {l0, l1, l2, l3};                                       \
            pH[kk2] = __builtin_bit_cast(short8, vh4);                          \
            pL[kk2] = __builtin_bit_cast(short8, vl4);                          \
        }                                                                       \
        /* PV(T): vbuf[PAR] */                                                  \
        {                                                                       \
            const char* vb = lds + 32768 + (PAR) * 16384;                       \
            __builtin_amdgcn_s_setprio(1);                                      \
            _Pragma("unroll")                                                   \
            for (int kk2 = 0; kk2 < 2; ++kk2) {                                 \
                _Pragma("unroll")                                               \
                for (int nt = 0; nt < 4; ++nt) {                                \
                    const int d = nt * 32 + l31;                                \
                    const int g = kk2 * 2 + h5;                                 \
                    const int off = d * 64 + ((g ^ (d & 3)) << 4);              \
                    short8 vh = *(const short8*)(vb + off);                     \
                    short8 vl = *(const short8*)(vb + 8192 + off);              \
                    o_[nt] = __builtin_amdgcn_mfma_f32_32x32x16_bf16(vh, pH[kk2], o_[nt], 0, 0, 0); \
                    o_[nt] = __builtin_amdgcn_mfma_f32_32x32x16_bf16(vl, pH[kk2], o_[nt], 0, 0, 0); \
                    o_[nt] = __builtin_amdgcn_mfma_f32_32x32x16_bf16(vh, pL[kk2], o_[nt], 0, 0, 0); \
                }                                                               \
            }                                                                   \
            __builtin_amdgcn_s_setprio(0);                                      \
        }                                                                       \
        __builtin_amdgcn_s_barrier();   /* kbuf[PAR^1],vbuf[PAR] reads done */  \
        __builtin_amdgcn_sched_barrier(0);                                      \
    }

    for (int tt = 0; tt < 32; tt += 2) {
        ATTN_ITER(tt,     sA, sB, 0)
        ATTN_ITER(tt + 1, sB, sA, 1)
    }
#undef ATTN_ITER

    asm volatile("s_waitcnt vmcnt(0)" ::: "memory");

    const float inv = 1.f / l_run;
#pragma unroll
    for (int nt = 0; nt < 4; ++nt)
#pragma unroll
        for (int r = 0; r < 16; ++r) {
            const int d = nt * 32 + (r & 3) + ((r >> 2) << 3) + h5 * 4;
            out[((size_t)b * 1024 + n * 128 + d) * PP + q] = o_[nt][r] * inv;
        }
}

// ============================================================================
extern "C" void kernel_launch(void* const* d_in, const int* in_sizes, int n_in,
                              void* d_out, int out_size, void* d_ws, size_t ws_size,
                              hipStream_t stream)
{
    const float* fm   = (const float*)d_in[0];
    const float* wqkv = (const float*)d_in[1];
    const float* relH = (const float*)d_in[2];
    const float* relW = (const float*)d_in[3];
    float* out = (float*)d_out;

    char* ws = (char*)d_ws;
    u16*  Qhi   = (u16*)(ws);
    u16*  Qlo   = (u16*)(ws + (16ull << 20));
    char* KIMG  = ws + (32ull << 20);
    char* VIMG  = ws + (64ull << 20);
    float* R    = (float*)(ws + (96ull << 20));
    char* FIMG  = ws + (96ull << 20);             // overlays R (dead before rel)
    char* AIMG  = ws + (112ull << 20);
    char* RELIMG= ws + (119ull << 20);

    wconv  <<<768, 256, 0, stream>>>(wqkv, AIMG);
    fmconv <<<dim3(16, 8, 8), 256, 0, stream>>>(fm, FIMG);
    relprep<<<8, 256, 0, stream>>>(relH, relW, RELIMG);
    qkv_gemm<<<dim3(8, 24, 8), 256, 0, stream>>>(AIMG, FIMG, Qhi, Qlo, KIMG, VIMG);
    rel_gemm<<<dim3(8, 64), 256, 0, stream>>>(Qhi, Qlo, RELIMG, R);
    attn_kernel<<<512, 256, 0, stream>>>(Qhi, Qlo, KIMG, VIMG, R, out);
}